// Round 9
// baseline (655.559 us; speedup 1.0000x reference)
//
#include <hip/hip_runtime.h>

// TS2Vec hierarchical contrastive loss — bf16 MFMA, raw-barrier pipelined LSE.
//
// R8 post-mortem: global_load_lds + __syncthreads = vmcnt(0) drain per tile
// (the m97 plateau mechanism); waves stalled on L2 latency every tile.
// R9: AITER-style staging — global_load -> VGPR -> ds_write, with RAW
// s_barrier preceded by lgkmcnt(0)-only wait (0xC07F): vmem loads stay in
// flight ACROSS barriers. 3 LDS buffers (61440 B), prefetch distance 2:
// segment ct: ds_write(tile ct+1; regs loaded at ct-1 => ~full-segment
// cover), issue loads(tile ct+2), ds_read+MFMA(tile ct), pipelined epilogue
// (dual accumulators cA/cB). Buffer distance 2 => one barrier per tile is
// WAR/RAW-safe. Block = 4 waves x 32 rows; A (whole K=320) in 80 regs/wave.
//
// Epilogue: fixed per-lane-row bias (init at always-slow tile 0), fast tile =
// fma+exp2+add; __any(f>60) rescue re-raises bias (exact: merge rescales
// (m,s); bias=FNEG lanes annihilated by exp2(FNEG-mt)=0).
// exp/log base-2 via __builtin_amdgcn_{exp2f,logf}. NOTE: never __exp2f/
// __log2f (glibc math.h reserved-name collision under hipcc g++ driver).
// Gram scales by the SQUARE of operand pre-scale: pyramid stays raw.

#define B_DIM 8
#define C_DIM 320
#define T_DIM 2048
#define NDEPTH 12
#define LOG2E 1.44269504088896340736f
#define LN2 0.69314718055994530942f
#define FNEG (-3.0e38f)
#define NBLK_TEMP 1448
#define NBLK_INST 256

typedef __attribute__((ext_vector_type(8))) short bf16x8;
typedef __attribute__((ext_vector_type(4))) float f32x4;

__device__ inline float fast_exp2(float x) { return __builtin_amdgcn_exp2f(x); }
__device__ inline float fast_log2(float x) { return __builtin_amdgcn_logf(x); }

// lgkmcnt(0)-ONLY wait (vmcnt=63, expcnt=7 untouched), then raw barrier.
// Keeps global loads in flight across the block barrier (AITER pattern).
__device__ inline void barrier_lgkm() {
  __builtin_amdgcn_s_waitcnt(0xC07F);
  __builtin_amdgcn_s_barrier();
}

__device__ inline float bf2f(unsigned short s) {
  unsigned u = ((unsigned)s) << 16;
  return __builtin_bit_cast(float, u);
}
__device__ inline unsigned short f2bf(float f) {
  unsigned u = __builtin_bit_cast(unsigned, f);
  u = (u + 0x7FFFu + ((u >> 16) & 1u)) >> 16;  // round-nearest-even
  return (unsigned short)u;
}
__device__ inline bf16x8 bmax8(bf16x8 a, bf16x8 b) {
  bf16x8 o;
#pragma unroll
  for (int k = 0; k < 8; ++k) {
    unsigned short ua = (unsigned short)a[k], ub = (unsigned short)b[k];
    o[k] = (short)(bf2f(ua) > bf2f(ub) ? ua : ub);
  }
  return o;
}

// ---------------- tiny utility kernels ----------------
__global__ void finalize_kernel(const float* __restrict__ acc, float* __restrict__ out) {
  if (threadIdx.x == 0) {
    float inst = acc[0] * (1.0f / 11.0f);
    float temp = acc[1] * (1.0f / 11.0f);
    out[0] = 0.5f * inst + 0.5f * temp;  // ALPHA = 0.5
    out[1] = inst;
    out[2] = temp;
  }
}

// ------- transpose+convert: [B][C][T]f32 -> [16][T][C]bf16; zeros acc ------
__global__ __launch_bounds__(256) void transpose_kernel(const float* __restrict__ z1,
                                                        const float* __restrict__ z2,
                                                        unsigned short* __restrict__ out,
                                                        float* __restrict__ acc) {
  if (blockIdx.x == 0 && blockIdx.y == 0 && blockIdx.z == 0 && threadIdx.x == 0 &&
      threadIdx.y == 0) {
    acc[0] = 0.f;
    acc[1] = 0.f;
  }
  __shared__ float tile[32][33];
  const int zi = blockIdx.z >> 3;
  const int b = blockIdx.z & 7;
  const float* in = zi ? z2 : z1;
  const int t0 = blockIdx.x * 32;
  const int c0 = blockIdx.y * 32;
  const int tx = threadIdx.x;
  const int ty = threadIdx.y;
#pragma unroll
  for (int k = 0; k < 4; ++k) {
    int c = c0 + ty + k * 8;
    tile[ty + k * 8][tx] = in[((size_t)b * C_DIM + c) * T_DIM + t0 + tx];
  }
  __syncthreads();
#pragma unroll
  for (int k = 0; k < 4; ++k) {
    int t = t0 + ty + k * 8;
    out[((size_t)(zi * B_DIM + b) * T_DIM + t) * C_DIM + c0 + tx] = f2bf(tile[tx][ty + k * 8]);
  }
}

// ---------------- max-pool: four levels in one pass -----------------------
__global__ __launch_bounds__(256) void pool4_kernel(const unsigned short* __restrict__ in,
                                                    unsigned short* __restrict__ o1,
                                                    unsigned short* __restrict__ o2,
                                                    unsigned short* __restrict__ o3,
                                                    unsigned short* __restrict__ o4,
                                                    int L4, int n8) {
  int idx = blockIdx.x * 256 + threadIdx.x;
  if (idx >= n8) return;
  int e = idx * 8;
  int c = e % C_DIM;
  int row = e / C_DIM;
  int bb = row / L4;
  int l = row % L4;
  const unsigned short* p = in + ((size_t)(bb * 16 * L4 + 16 * l)) * C_DIM + c;
  bf16x8 v[16];
#pragma unroll
  for (int k = 0; k < 16; ++k) v[k] = *(const bf16x8*)(p + (size_t)k * C_DIM);
  bf16x8 m1[8], m2[4], m3[2], m4;
#pragma unroll
  for (int j = 0; j < 8; ++j) m1[j] = bmax8(v[2 * j], v[2 * j + 1]);
#pragma unroll
  for (int j = 0; j < 4; ++j) m2[j] = bmax8(m1[2 * j], m1[2 * j + 1]);
#pragma unroll
  for (int j = 0; j < 2; ++j) m3[j] = bmax8(m2[2 * j], m2[2 * j + 1]);
  m4 = bmax8(m3[0], m3[1]);
#pragma unroll
  for (int j = 0; j < 8; ++j)
    *(bf16x8*)(o1 + ((size_t)(bb * 8 * L4 + 8 * l + j)) * C_DIM + c) = m1[j];
#pragma unroll
  for (int j = 0; j < 4; ++j)
    *(bf16x8*)(o2 + ((size_t)(bb * 4 * L4 + 4 * l + j)) * C_DIM + c) = m2[j];
#pragma unroll
  for (int j = 0; j < 2; ++j)
    *(bf16x8*)(o3 + ((size_t)(bb * 2 * L4 + 2 * l + j)) * C_DIM + c) = m3[j];
  *(bf16x8*)(o4 + ((size_t)(bb * L4 + l)) * C_DIM + c) = m4;
}

// ---------------- max-pool: three levels in one pass ----------------------
__global__ __launch_bounds__(256) void pool3_kernel(const unsigned short* __restrict__ in,
                                                    unsigned short* __restrict__ o1,
                                                    unsigned short* __restrict__ o2,
                                                    unsigned short* __restrict__ o3,
                                                    int L3, int n8) {
  int idx = blockIdx.x * 256 + threadIdx.x;
  if (idx >= n8) return;
  int e = idx * 8;
  int c = e % C_DIM;
  int row = e / C_DIM;
  int bb = row / L3;
  int l = row % L3;
  const unsigned short* p = in + ((size_t)(bb * 8 * L3 + 8 * l)) * C_DIM + c;
  bf16x8 v[8];
#pragma unroll
  for (int k = 0; k < 8; ++k) v[k] = *(const bf16x8*)(p + (size_t)k * C_DIM);
  bf16x8 m1[4], m2[2], m3;
#pragma unroll
  for (int j = 0; j < 4; ++j) m1[j] = bmax8(v[2 * j], v[2 * j + 1]);
#pragma unroll
  for (int j = 0; j < 2; ++j) m2[j] = bmax8(m1[2 * j], m1[2 * j + 1]);
  m3 = bmax8(m2[0], m2[1]);
#pragma unroll
  for (int j = 0; j < 4; ++j)
    *(bf16x8*)(o1 + ((size_t)(bb * 4 * L3 + 4 * l + j)) * C_DIM + c) = m1[j];
#pragma unroll
  for (int j = 0; j < 2; ++j)
    *(bf16x8*)(o2 + ((size_t)(bb * 2 * L3 + 2 * l + j)) * C_DIM + c) = m2[j];
  *(bf16x8*)(o3 + ((size_t)(bb * L3 + l)) * C_DIM + c) = m3;
}

// ---------------- fused temp + inst loss ----------------------------------
__global__ __launch_bounds__(256, 2) void temp_kernel(const unsigned short* __restrict__ pyr,
                                                      float2* __restrict__ ent,
                                                      float* __restrict__ acc) {
  constexpr int Ls[NDEPTH] = {2048, 1024, 512, 256, 128, 64, 32, 16, 8, 4, 2, 1};
  constexpr int SP[NDEPTH] = {4, 2, 1, 1, 1, 1, 1, 1, 1, 1, 1, 1};
  constexpr int NB[NDEPTH] = {1024, 256, 64, 32, 16, 8, 8, 8, 8, 8, 8, 8};
  constexpr size_t ZOFF[NDEPTH] = {0,        10485760, 15728640, 18350080,
                                   19660800, 20316160, 20643840, 20807680,
                                   20889600, 20930560, 20951040, 20961280};
  constexpr size_t EBASE[NDEPTH] = {0,      131072, 163840, 172032, 176128, 178176,
                                    179200, 179712, 179968, 180096, 180160, 180192};
  constexpr float SCL[NDEPTH] = {
      1.f / (16 * 2048.f), 1.f / (16 * 1024.f), 1.f / (16 * 512.f), 1.f / (16 * 256.f),
      1.f / (16 * 128.f),  1.f / (16 * 64.f),   1.f / (16 * 32.f),  1.f / (16 * 16.f),
      1.f / (16 * 8.f),    1.f / (16 * 4.f),    1.f / (16 * 2.f),   1.f / (16 * 1.f)};

  __shared__ __align__(16) unsigned short Bs[3 * 10240];  // 61440 B, 3 buffers

  const int tid = threadIdx.x;
  const int w = tid >> 6, lane = tid & 63;
  const int lr = lane & 15, lg = lane >> 4;

  // ================= inst path (blocks >= NBLK_TEMP) =================
  if (blockIdx.x >= NBLK_TEMP) {
    const int gw = (blockIdx.x - NBLK_TEMP) * 4 + w;
    const int nw = NBLK_INST * 4;
    float partial = 0.f;
    for (int gl = gw; gl < 4095; gl += nw) {
      int d = 0, l = gl;
      while (l >= Ls[d]) { l -= Ls[d]; ++d; }
      const int L = Ls[d];
      const unsigned short* Z = pyr + ZOFF[d];
      const unsigned short* rp = Z + ((size_t)lr * L + l) * C_DIM + lg * 8;
      bf16x8 fr[10];
#pragma unroll
      for (int ks = 0; ks < 10; ++ks) fr[ks] = *(const bf16x8*)(rp + ks * 32);
      f32x4 c4 = (f32x4){0.f, 0.f, 0.f, 0.f};
#pragma unroll
      for (int ks = 0; ks < 10; ++ks)
        c4 = __builtin_amdgcn_mfma_f32_16x16x32_bf16(fr[ks], fr[ks], c4, 0, 0, 0);
#pragma unroll
      for (int rg = 0; rg < 4; ++rg) {
        int gr = lg * 4 + rg, gc = lr;
        float v = c4[rg];
        int prt = (gr + 8) & 15;
        float ps = (gc == prt) ? v : 0.f;
        float x = (gc != gr) ? v * LOG2E : FNEG;
        float mx = x;
#pragma unroll
        for (int k = 1; k < 16; k <<= 1) mx = fmaxf(mx, __shfl_xor(mx, k));
        float se = fast_exp2(fmaxf(x - mx, -128.f));
#pragma unroll
        for (int k = 1; k < 16; k <<= 1) {
          se += __shfl_xor(se, k);
          ps += __shfl_xor(ps, k);
        }
        if (lr == 0) partial += ((mx + fast_log2(se)) * LN2 - ps) * SCL[d];
      }
    }
#pragma unroll
    for (int k = 1; k < 64; k <<= 1) partial += __shfl_xor(partial, k);
    if (lane == 0) atomicAdd(acc, partial);
    return;
  }

  // ================= temp path =================
  int bid = blockIdx.x;
  int d = 0;
  while (bid >= NB[d]) { bid -= NB[d]; ++d; }
  const int L = Ls[d], M = 2 * L, sp = SP[d];
  const int csz = M / sp;
  const int ntiles = (csz + 31) >> 5;
  const int b = bid & 7;  // batch fastest -> XCD L2 affinity
  const int t2 = bid >> 3;
  const int chunk = t2 % sp;
  const int rb = t2 / sp;
  const int r0 = rb * 128;
  const int cbase = chunk * csz;
  const float scale = SCL[d];
  const unsigned short* Z = pyr + ZOFF[d];

  auto rowptr = [&](int r) -> const unsigned short* {
    r = (r < M) ? r : (M - 1);
    int idx = (r < L) ? (b * L + r) : ((B_DIM + b) * L + (r - L));
    return Z + (size_t)idx * C_DIM;
  };

  // A fragments: this wave's 32 rows, whole K (80 regs) — issue early
  const int rwave = r0 + w * 32;
  bf16x8 afrag[2][10];
#pragma unroll
  for (int rs = 0; rs < 2; ++rs) {
    const unsigned short* rp = rowptr(rwave + rs * 16 + lr) + lg * 8;
#pragma unroll
    for (int ks = 0; ks < 10; ++ks) afrag[rs][ks] = *(const bf16x8*)(rp + ks * 32);
  }

  // staging pointers: per-blob, advance 32 cols/tile, +7*L*C at half boundary
  const long stepEl = 32 * (long)C_DIM;
  const long extraEl = (long)7 * L * C_DIM;
  const unsigned short* gp[5];
#pragma unroll
  for (int i = 0; i < 5; ++i) {
    int blob = w * 5 + i, ks = blob >> 1, sub = blob & 1;
    int c = cbase + sub * 16 + lr;
    c = (c < M) ? c : (M - 1);
    long idx = (long)b * L + c + ((c >= L) ? (long)7 * L : 0);
    gp[i] = Z + idx * C_DIM + ks * 32 + lg * 8;
  }
  int c0next = cbase;
  auto adv = [&]() {
    long a = stepEl;
    c0next += 32;
    if (c0next == L) a += extraEl;
#pragma unroll
    for (int i = 0; i < 5; ++i) gp[i] += a;
  };

  // two staging register sets: tile t lives in set (t&1)
  bf16x8 sA[5], sB[5];
  auto ldGA = [&]() {
#pragma unroll
    for (int i = 0; i < 5; ++i) sA[i] = *(const bf16x8*)gp[i];
    adv();
  };
  auto ldGB = [&]() {
#pragma unroll
    for (int i = 0; i < 5; ++i) sB[i] = *(const bf16x8*)gp[i];
    adv();
  };
  auto dsWA = [&](int buf) {
#pragma unroll
    for (int i = 0; i < 5; ++i)
      *(bf16x8*)&Bs[buf * 10240 + (w * 5 + i) * 512 + lane * 8] = sA[i];
  };
  auto dsWB = [&](int buf) {
#pragma unroll
    for (int i = 0; i < 5; ++i)
      *(bf16x8*)&Bs[buf * 10240 + (w * 5 + i) * 512 + lane * 8] = sB[i];
  };

  auto mfmaTile = [&](int buf, f32x4 (&cc)[2][2]) {
#pragma unroll
    for (int rs = 0; rs < 2; ++rs)
#pragma unroll
      for (int cs = 0; cs < 2; ++cs) cc[rs][cs] = (f32x4){0.f, 0.f, 0.f, 0.f};
#pragma unroll
    for (int ks = 0; ks < 10; ++ks) {
      bf16x8 b0 = *(const bf16x8*)&Bs[buf * 10240 + (ks * 2 + 0) * 512 + lane * 8];
      bf16x8 b1 = *(const bf16x8*)&Bs[buf * 10240 + (ks * 2 + 1) * 512 + lane * 8];
#pragma unroll
      for (int rs = 0; rs < 2; ++rs) {
        cc[rs][0] = __builtin_amdgcn_mfma_f32_16x16x32_bf16(afrag[rs][ks], b0, cc[rs][0], 0, 0, 0);
        cc[rs][1] = __builtin_amdgcn_mfma_f32_16x16x32_bf16(afrag[rs][ks], b1, cc[rs][1], 0, 0, 0);
      }
    }
  };

  // wave-uniform slow-tile ranges
  const int rlo = rwave, rhi = rwave + 31;
  int plo = 1, phi = 0;  // empty
  if (d <= 5) {          // L>=64, rwave%32==0 -> rows lie in one half
    plo = (rlo < L) ? rlo + L : rlo - L;
    phi = plo + 31;
  }

  // per-lane per-row state: fixed bias (raw), bias*log2e, sum
  float bias[8], bl2[8], s_[8];
  float pacc = 0.f;
#pragma unroll
  for (int i = 0; i < 8; ++i) { bias[i] = FNEG; bl2[i] = 0.f; s_[i] = 0.f; }

  auto epiSlow = [&](f32x4 (&cp)[2][2], int eclo) {
    const int gc0 = eclo + lr, gc1 = gc0 + 16;
#pragma unroll
    for (int rs = 0; rs < 2; ++rs) {
#pragma unroll
      for (int rg = 0; rg < 4; ++rg) {
        int i = rs * 4 + rg;
        int gr = rwave + rs * 16 + lg * 4 + rg;
        int prt = (gr < L) ? (gr + L) : (gr - L);
        float v0 = cp[rs][0][rg], v1 = cp[rs][1][rg];
        if (gr < M) {
          if (gc0 == prt) pacc += v0;
          if (gc1 == prt) pacc += v1;
        }
        float x0 = (gc0 < M && gc0 != gr) ? v0 : FNEG;
        float x1 = (gc1 < M && gc1 != gr) ? v1 : FNEG;
        float mn = fmaxf(bias[i], fmaxf(x0, x1));
        s_[i] = s_[i] * fast_exp2((bias[i] - mn) * LOG2E) +
                fast_exp2((x0 - mn) * LOG2E) + fast_exp2((x1 - mn) * LOG2E);
        bias[i] = mn;
      }
    }
#pragma unroll
    for (int i = 0; i < 8; ++i) bl2[i] = bias[i] * LOG2E;
  };

  auto epiFast = [&](f32x4 (&cp)[2][2]) {
    float flag = FNEG;
#pragma unroll
    for (int rs = 0; rs < 2; ++rs) {
#pragma unroll
      for (int rg = 0; rg < 4; ++rg) {
        int i = rs * 4 + rg;
        float f0 = __builtin_fmaf(cp[rs][0][rg], LOG2E, -bl2[i]);
        float f1 = __builtin_fmaf(cp[rs][1][rg], LOG2E, -bl2[i]);
        cp[rs][0][rg] = f0;
        cp[rs][1][rg] = f1;
        flag = fmaxf(flag, fmaxf(f0, f1));
      }
    }
    if (__any(flag > 60.f)) {  // rare: raise bias online
#pragma unroll
      for (int rs = 0; rs < 2; ++rs) {
#pragma unroll
        for (int rg = 0; rg < 4; ++rg) {
          int i = rs * 4 + rg;
          float v0 = (cp[rs][0][rg] + bl2[i]) * LN2;
          float v1 = (cp[rs][1][rg] + bl2[i]) * LN2;
          float mn = fmaxf(bias[i], fmaxf(v0, v1));
          s_[i] = s_[i] * fast_exp2((bias[i] - mn) * LOG2E) +
                  fast_exp2((v0 - mn) * LOG2E) + fast_exp2((v1 - mn) * LOG2E);
          bias[i] = mn;
        }
      }
#pragma unroll
      for (int i = 0; i < 8; ++i) bl2[i] = bias[i] * LOG2E;
    } else {
#pragma unroll
      for (int rs = 0; rs < 2; ++rs)
#pragma unroll
        for (int rg = 0; rg < 4; ++rg)
          s_[rs * 4 + rg] += fast_exp2(cp[rs][0][rg]) + fast_exp2(cp[rs][1][rg]);
    }
  };

  auto epi = [&](f32x4 (&cp)[2][2], int et) {
    const int eclo = cbase + et * 32, echi = eclo + 31;
    bool slowT = (et == 0) || (d >= 6) ||
                 (echi >= rlo && eclo <= rhi) ||   // diagonal in tile
                 (echi >= plo && eclo <= phi);     // partner col in tile
    if (slowT) epiSlow(cp, eclo); else epiFast(cp);
  };

  // ---- main loop: raw barriers, loads in flight across them ----
  f32x4 cA[2][2], cB[2][2];
  ldGA();                     // tile 0 -> setA
  dsWA(0);                    // buf 0
  if (ntiles > 1) ldGB();     // tile 1 -> setB (stays in flight)
  barrier_lgkm();

  int br = 0;                 // read-buffer for tile ct
  for (int ct = 0; ct < ntiles; ++ct) {
    int bw = (br == 2) ? 0 : br + 1;   // write-buffer (tile ct+1)
    if (ct + 1 < ntiles) {
      if ((ct + 1) & 1) dsWB(bw); else dsWA(bw);  // waits vmcnt for that set only
    }
    if (ct + 2 < ntiles) {
      if ((ct + 2) & 1) ldGB(); else ldGA();      // prefetch distance 2
    }
    if (ct & 1) {
      mfmaTile(br, cB);
      epi(cA, ct - 1);
    } else {
      mfmaTile(br, cA);
      if (ct > 0) epi(cB, ct - 1);
    }
    barrier_lgkm();           // lgkmcnt(0) only; vmem prefetch crosses freely
    br = bw;
  }
  if ((ntiles - 1) & 1) epi(cB, ntiles - 1); else epi(cA, ntiles - 1);

  // merge (bias,s) across the 16 lr-lanes per row, write per-row-chunk partial
#pragma unroll
  for (int rs = 0; rs < 2; ++rs) {
#pragma unroll
    for (int rg = 0; rg < 4; ++rg) {
      int i = rs * 4 + rg;
      float m = bias[i], s = s_[i];
      float mt = m;
#pragma unroll
      for (int k = 1; k < 16; k <<= 1) mt = fmaxf(mt, __shfl_xor(mt, k));
      float st = s * fast_exp2((m - mt) * LOG2E);  // bias=FNEG lanes -> 0
#pragma unroll
      for (int k = 1; k < 16; k <<= 1) st += __shfl_xor(st, k);
      int gr = rwave + rs * 16 + lg * 4 + rg;
      if (gr < M && lr == 0)
        ent[EBASE[d] + ((size_t)(b * M + gr)) * sp + chunk] = make_float2(mt, st);
    }
  }

  // positives (slow tiles only): one atomic per wave
#pragma unroll
  for (int k = 1; k < 64; k <<= 1) pacc += __shfl_xor(pacc, k);
  if (lane == 0) atomicAdd(acc + 1, -pacc * scale);
}

// ---------------- merge column-chunk partials -> temp loss ----------------
__global__ __launch_bounds__(256) void merge_kernel(const float2* __restrict__ ent,
                                                    float* __restrict__ acc) {
  constexpr int Ls[NDEPTH] = {2048, 1024, 512, 256, 128, 64, 32, 16, 8, 4, 2, 1};
  constexpr int SP[NDEPTH] = {4, 2, 1, 1, 1, 1, 1, 1, 1, 1, 1, 1};
  constexpr size_t EBASE[NDEPTH] = {0,      131072, 163840, 172032, 176128, 178176,
                                    179200, 179712, 179968, 180096, 180160, 180192};
  constexpr int RBASE[NDEPTH] = {0,     32768, 49152, 57344, 61440, 63488,
                                 64512, 65024, 65280, 65408, 65472, 65504};
  __shared__ float red[4];
  int i = blockIdx.x * 256 + threadIdx.x;
  float partial = 0.f;
  if (i < 65520) {
    int d = 0;
    while (d < 11 && i >= RBASE[d + 1]) ++d;
    int rem = i - RBASE[d];
    int sp = SP[d];
    const float2* e = ent + EBASE[d] + (size_t)rem * sp;
    float mt = FNEG;
    for (int c = 0; c < sp; ++c) mt = fmaxf(mt, e[c].x);
    float st = 0.f;
    for (int c = 0; c < sp; ++c) st += e[c].y * fast_exp2((e[c].x - mt) * LOG2E);
    partial = (mt + LN2 * fast_log2(st)) / (16.f * (float)Ls[d]);
  }
#pragma unroll
  for (int k = 1; k < 64; k <<= 1) partial += __shfl_xor(partial, k);
  if ((threadIdx.x & 63) == 0) red[threadIdx.x >> 6] = partial;
  __syncthreads();
  if (threadIdx.x == 0) atomicAdd(acc + 1, red[0] + red[1] + red[2] + red[3]);
}

// ---------------- launch ----------------
extern "C" void kernel_launch(void* const* d_in, const int* in_sizes, int n_in,
                              void* d_out, int out_size, void* d_ws, size_t ws_size,
                              hipStream_t stream) {
  const float* z1 = (const float*)d_in[0];
  const float* z2 = (const float*)d_in[1];
  float* out = (float*)d_out;
  float* acc = (float*)d_ws;                   // [0]=inst, [1]=temp
  float2* ent = (float2*)((char*)d_ws + 256);  // 180208 used, pad to 180224
  unsigned short* pyr = (unsigned short*)((char*)d_ws + 256 + (size_t)180224 * 8);

  constexpr size_t ZOFF[NDEPTH] = {0,        10485760, 15728640, 18350080,
                                   19660800, 20316160, 20643840, 20807680,
                                   20889600, 20930560, 20951040, 20961280};

  transpose_kernel<<<dim3(T_DIM / 32, C_DIM / 32, 16), dim3(32, 8), 0, stream>>>(
      z1, z2, pyr, acc);

  // pools fused: d0->d1..d4, d4->d5..d8, d8->d9..d11
  {
    int L4 = 128, n8 = 16 * L4 * C_DIM / 8;  // 81920
    pool4_kernel<<<dim3((n8 + 255) / 256), 256, 0, stream>>>(
        pyr + ZOFF[0], pyr + ZOFF[1], pyr + ZOFF[2], pyr + ZOFF[3], pyr + ZOFF[4], L4, n8);
  }
  {
    int L4 = 8, n8 = 16 * L4 * C_DIM / 8;    // 5120
    pool4_kernel<<<dim3((n8 + 255) / 256), 256, 0, stream>>>(
        pyr + ZOFF[4], pyr + ZOFF[5], pyr + ZOFF[6], pyr + ZOFF[7], pyr + ZOFF[8], L4, n8);
  }
  {
    int L3 = 1, n8 = 16 * L3 * C_DIM / 8;    // 640
    pool3_kernel<<<dim3((n8 + 255) / 256), 256, 0, stream>>>(
        pyr + ZOFF[8], pyr + ZOFF[9], pyr + ZOFF[10], pyr + ZOFF[11], L3, n8);
  }

  temp_kernel<<<dim3(NBLK_TEMP + NBLK_INST), 256, 0, stream>>>(pyr, ent, acc);
  merge_kernel<<<dim3(256), 256, 0, stream>>>(ent, acc);

  finalize_kernel<<<1, 64, 0, stream>>>(acc, out);
}

// Round 10
// 448.189 us; speedup vs baseline: 1.4627x; 1.4627x over previous
//
#include <hip/hip_runtime.h>

// TS2Vec hierarchical contrastive loss — bf16 MFMA, AITER-style staging.
//
// R8: global_load_lds + __syncthreads -> compiler emits s_waitcnt vmcnt(0)
// before every barrier = prefetch drained per tile (m97 plateau). R9: dual
// staging reg sets (+40 regs, cross-barrier live) -> spilled 409MB scratch.
// R10: ONE staging set (20 VGPR, live exactly one iteration): tile ct+2 is
// global_load'ed at iter ct into `set`, ds_written at iter ct+1 (one full
// epoch of latency cover; compiler's vmcnt wait before ds_write is register-
// exact), MFMA'd at iter ct+2. 3 LDS buffers (61440 B ring, distance 2) make
// one raw barrier per tile RAW/WAR-safe. Barrier = lgkmcnt(0)-only wait
// (0xC07F) + s_barrier: vmem loads stay in flight across it.
// Register diet: LSE bias kept ONLY in base-2 domain (m2[8]; no bl2 array).
//
// Block = 4 waves x 32 rows; A (whole K=320) in 80 regs/wave; pipelined
// epilogue (dual accumulators cA/cB: MFMA(ct) overlaps epilogue(ct-1)).
// Fast tile = fma+exp2+add per entry; __any(f>60) rescue re-raises bias
// (exact: merge kernel rescales (m,s); m2=FNEG lanes annihilated by
// exp2(FNEG-mt)=0; junk sums from all-masked prefixes annihilated by
// s*exp2(FNEG-real)=0 on first real entry).
// exp/log base-2 via __builtin_amdgcn_{exp2f,logf}. NOTE: never __exp2f/
// __log2f (glibc math.h reserved-name collision under hipcc g++ driver).
// Gram scales by the SQUARE of operand pre-scale: pyramid stays raw.

#define B_DIM 8
#define C_DIM 320
#define T_DIM 2048
#define NDEPTH 12
#define LOG2E 1.44269504088896340736f
#define LN2 0.69314718055994530942f
#define FNEG (-3.0e38f)
#define NBLK_TEMP 1448
#define NBLK_INST 256

typedef __attribute__((ext_vector_type(8))) short bf16x8;
typedef __attribute__((ext_vector_type(4))) float f32x4;

__device__ inline float fast_exp2(float x) { return __builtin_amdgcn_exp2f(x); }
__device__ inline float fast_log2(float x) { return __builtin_amdgcn_logf(x); }

// lgkmcnt(0)-ONLY wait (vmcnt untouched), then raw barrier: vmem prefetch
// issued before this crosses the barrier still in flight (AITER pattern).
__device__ inline void barrier_lgkm() {
  __builtin_amdgcn_s_waitcnt(0xC07F);
  __builtin_amdgcn_s_barrier();
}

__device__ inline float bf2f(unsigned short s) {
  unsigned u = ((unsigned)s) << 16;
  return __builtin_bit_cast(float, u);
}
__device__ inline unsigned short f2bf(float f) {
  unsigned u = __builtin_bit_cast(unsigned, f);
  u = (u + 0x7FFFu + ((u >> 16) & 1u)) >> 16;  // round-nearest-even
  return (unsigned short)u;
}
__device__ inline bf16x8 bmax8(bf16x8 a, bf16x8 b) {
  bf16x8 o;
#pragma unroll
  for (int k = 0; k < 8; ++k) {
    unsigned short ua = (unsigned short)a[k], ub = (unsigned short)b[k];
    o[k] = (short)(bf2f(ua) > bf2f(ub) ? ua : ub);
  }
  return o;
}

// ---------------- tiny utility kernels ----------------
__global__ void finalize_kernel(const float* __restrict__ acc, float* __restrict__ out) {
  if (threadIdx.x == 0) {
    float inst = acc[0] * (1.0f / 11.0f);
    float temp = acc[1] * (1.0f / 11.0f);
    out[0] = 0.5f * inst + 0.5f * temp;  // ALPHA = 0.5
    out[1] = inst;
    out[2] = temp;
  }
}

// ------- transpose+convert: [B][C][T]f32 -> [16][T][C]bf16; zeros acc ------
__global__ __launch_bounds__(256) void transpose_kernel(const float* __restrict__ z1,
                                                        const float* __restrict__ z2,
                                                        unsigned short* __restrict__ out,
                                                        float* __restrict__ acc) {
  if (blockIdx.x == 0 && blockIdx.y == 0 && blockIdx.z == 0 && threadIdx.x == 0 &&
      threadIdx.y == 0) {
    acc[0] = 0.f;
    acc[1] = 0.f;
  }
  __shared__ float tile[32][33];
  const int zi = blockIdx.z >> 3;
  const int b = blockIdx.z & 7;
  const float* in = zi ? z2 : z1;
  const int t0 = blockIdx.x * 32;
  const int c0 = blockIdx.y * 32;
  const int tx = threadIdx.x;
  const int ty = threadIdx.y;
#pragma unroll
  for (int k = 0; k < 4; ++k) {
    int c = c0 + ty + k * 8;
    tile[ty + k * 8][tx] = in[((size_t)b * C_DIM + c) * T_DIM + t0 + tx];
  }
  __syncthreads();
#pragma unroll
  for (int k = 0; k < 4; ++k) {
    int t = t0 + ty + k * 8;
    out[((size_t)(zi * B_DIM + b) * T_DIM + t) * C_DIM + c0 + tx] = f2bf(tile[tx][ty + k * 8]);
  }
}

// ---------------- max-pool: four levels in one pass -----------------------
__global__ __launch_bounds__(256) void pool4_kernel(const unsigned short* __restrict__ in,
                                                    unsigned short* __restrict__ o1,
                                                    unsigned short* __restrict__ o2,
                                                    unsigned short* __restrict__ o3,
                                                    unsigned short* __restrict__ o4,
                                                    int L4, int n8) {
  int idx = blockIdx.x * 256 + threadIdx.x;
  if (idx >= n8) return;
  int e = idx * 8;
  int c = e % C_DIM;
  int row = e / C_DIM;
  int bb = row / L4;
  int l = row % L4;
  const unsigned short* p = in + ((size_t)(bb * 16 * L4 + 16 * l)) * C_DIM + c;
  bf16x8 v[16];
#pragma unroll
  for (int k = 0; k < 16; ++k) v[k] = *(const bf16x8*)(p + (size_t)k * C_DIM);
  bf16x8 m1[8], m2[4], m3[2], m4;
#pragma unroll
  for (int j = 0; j < 8; ++j) m1[j] = bmax8(v[2 * j], v[2 * j + 1]);
#pragma unroll
  for (int j = 0; j < 4; ++j) m2[j] = bmax8(m1[2 * j], m1[2 * j + 1]);
#pragma unroll
  for (int j = 0; j < 2; ++j) m3[j] = bmax8(m2[2 * j], m2[2 * j + 1]);
  m4 = bmax8(m3[0], m3[1]);
#pragma unroll
  for (int j = 0; j < 8; ++j)
    *(bf16x8*)(o1 + ((size_t)(bb * 8 * L4 + 8 * l + j)) * C_DIM + c) = m1[j];
#pragma unroll
  for (int j = 0; j < 4; ++j)
    *(bf16x8*)(o2 + ((size_t)(bb * 4 * L4 + 4 * l + j)) * C_DIM + c) = m2[j];
#pragma unroll
  for (int j = 0; j < 2; ++j)
    *(bf16x8*)(o3 + ((size_t)(bb * 2 * L4 + 2 * l + j)) * C_DIM + c) = m3[j];
  *(bf16x8*)(o4 + ((size_t)(bb * L4 + l)) * C_DIM + c) = m4;
}

// ---------------- max-pool: three levels in one pass ----------------------
__global__ __launch_bounds__(256) void pool3_kernel(const unsigned short* __restrict__ in,
                                                    unsigned short* __restrict__ o1,
                                                    unsigned short* __restrict__ o2,
                                                    unsigned short* __restrict__ o3,
                                                    int L3, int n8) {
  int idx = blockIdx.x * 256 + threadIdx.x;
  if (idx >= n8) return;
  int e = idx * 8;
  int c = e % C_DIM;
  int row = e / C_DIM;
  int bb = row / L3;
  int l = row % L3;
  const unsigned short* p = in + ((size_t)(bb * 8 * L3 + 8 * l)) * C_DIM + c;
  bf16x8 v[8];
#pragma unroll
  for (int k = 0; k < 8; ++k) v[k] = *(const bf16x8*)(p + (size_t)k * C_DIM);
  bf16x8 m1[4], m2[2], m3;
#pragma unroll
  for (int j = 0; j < 4; ++j) m1[j] = bmax8(v[2 * j], v[2 * j + 1]);
#pragma unroll
  for (int j = 0; j < 2; ++j) m2[j] = bmax8(m1[2 * j], m1[2 * j + 1]);
  m3 = bmax8(m2[0], m2[1]);
#pragma unroll
  for (int j = 0; j < 4; ++j)
    *(bf16x8*)(o1 + ((size_t)(bb * 4 * L3 + 4 * l + j)) * C_DIM + c) = m1[j];
#pragma unroll
  for (int j = 0; j < 2; ++j)
    *(bf16x8*)(o2 + ((size_t)(bb * 2 * L3 + 2 * l + j)) * C_DIM + c) = m2[j];
  *(bf16x8*)(o3 + ((size_t)(bb * L3 + l)) * C_DIM + c) = m3;
}

// ---------------- fused temp + inst loss ----------------------------------
__global__ __launch_bounds__(256, 2) void temp_kernel(const unsigned short* __restrict__ pyr,
                                                      float2* __restrict__ ent,
                                                      float* __restrict__ acc) {
  constexpr int Ls[NDEPTH] = {2048, 1024, 512, 256, 128, 64, 32, 16, 8, 4, 2, 1};
  constexpr int SP[NDEPTH] = {4, 2, 1, 1, 1, 1, 1, 1, 1, 1, 1, 1};
  constexpr int NB[NDEPTH] = {1024, 256, 64, 32, 16, 8, 8, 8, 8, 8, 8, 8};
  constexpr size_t ZOFF[NDEPTH] = {0,        10485760, 15728640, 18350080,
                                   19660800, 20316160, 20643840, 20807680,
                                   20889600, 20930560, 20951040, 20961280};
  constexpr size_t EBASE[NDEPTH] = {0,      131072, 163840, 172032, 176128, 178176,
                                    179200, 179712, 179968, 180096, 180160, 180192};
  constexpr float SCL[NDEPTH] = {
      1.f / (16 * 2048.f), 1.f / (16 * 1024.f), 1.f / (16 * 512.f), 1.f / (16 * 256.f),
      1.f / (16 * 128.f),  1.f / (16 * 64.f),   1.f / (16 * 32.f),  1.f / (16 * 16.f),
      1.f / (16 * 8.f),    1.f / (16 * 4.f),    1.f / (16 * 2.f),   1.f / (16 * 1.f)};

  __shared__ __align__(16) unsigned short Bs[3 * 10240];  // 61440 B, 3-buffer ring

  const int tid = threadIdx.x;
  const int w = tid >> 6, lane = tid & 63;
  const int lr = lane & 15, lg = lane >> 4;

  // ================= inst path (blocks >= NBLK_TEMP) =================
  if (blockIdx.x >= NBLK_TEMP) {
    const int gw = (blockIdx.x - NBLK_TEMP) * 4 + w;
    const int nw = NBLK_INST * 4;
    float partial = 0.f;
    for (int gl = gw; gl < 4095; gl += nw) {
      int d = 0, l = gl;
      while (l >= Ls[d]) { l -= Ls[d]; ++d; }
      const int L = Ls[d];
      const unsigned short* Z = pyr + ZOFF[d];
      const unsigned short* rp = Z + ((size_t)lr * L + l) * C_DIM + lg * 8;
      bf16x8 fr[10];
#pragma unroll
      for (int ks = 0; ks < 10; ++ks) fr[ks] = *(const bf16x8*)(rp + ks * 32);
      f32x4 c4 = (f32x4){0.f, 0.f, 0.f, 0.f};
#pragma unroll
      for (int ks = 0; ks < 10; ++ks)
        c4 = __builtin_amdgcn_mfma_f32_16x16x32_bf16(fr[ks], fr[ks], c4, 0, 0, 0);
#pragma unroll
      for (int rg = 0; rg < 4; ++rg) {
        int gr = lg * 4 + rg, gc = lr;
        float v = c4[rg];
        int prt = (gr + 8) & 15;
        float ps = (gc == prt) ? v : 0.f;
        float x = (gc != gr) ? v * LOG2E : FNEG;
        float mx = x;
#pragma unroll
        for (int k = 1; k < 16; k <<= 1) mx = fmaxf(mx, __shfl_xor(mx, k));
        float se = fast_exp2(fmaxf(x - mx, -128.f));
#pragma unroll
        for (int k = 1; k < 16; k <<= 1) {
          se += __shfl_xor(se, k);
          ps += __shfl_xor(ps, k);
        }
        if (lr == 0) partial += ((mx + fast_log2(se)) * LN2 - ps) * SCL[d];
      }
    }
#pragma unroll
    for (int k = 1; k < 64; k <<= 1) partial += __shfl_xor(partial, k);
    if (lane == 0) atomicAdd(acc, partial);
    return;
  }

  // ================= temp path =================
  int bid = blockIdx.x;
  int d = 0;
  while (bid >= NB[d]) { bid -= NB[d]; ++d; }
  const int L = Ls[d], M = 2 * L, sp = SP[d];
  const int csz = M / sp;
  const int ntiles = (csz + 31) >> 5;
  const int b = bid & 7;  // batch fastest -> XCD L2 affinity
  const int t2 = bid >> 3;
  const int chunk = t2 % sp;
  const int rb = t2 / sp;
  const int r0 = rb * 128;
  const int cbase = chunk * csz;
  const float scale = SCL[d];
  const unsigned short* Z = pyr + ZOFF[d];

  auto rowptr = [&](int r) -> const unsigned short* {
    r = (r < M) ? r : (M - 1);
    int idx = (r < L) ? (b * L + r) : ((B_DIM + b) * L + (r - L));
    return Z + (size_t)idx * C_DIM;
  };

  // A fragments: this wave's 32 rows, whole K (80 regs) — issue early
  const int rwave = r0 + w * 32;
  bf16x8 afrag[2][10];
#pragma unroll
  for (int rs = 0; rs < 2; ++rs) {
    const unsigned short* rp = rowptr(rwave + rs * 16 + lr) + lg * 8;
#pragma unroll
    for (int ks = 0; ks < 10; ++ks) afrag[rs][ks] = *(const bf16x8*)(rp + ks * 32);
  }

  // staging pointers: per-blob, advance 32 cols/tile, +7*L*C at half boundary
  const long stepEl = 32 * (long)C_DIM;
  const long extraEl = (long)7 * L * C_DIM;
  const unsigned short* gp[5];
#pragma unroll
  for (int i = 0; i < 5; ++i) {
    int blob = w * 5 + i, ks = blob >> 1, sub = blob & 1;
    int c = cbase + sub * 16 + lr;
    c = (c < M) ? c : (M - 1);
    long idx = (long)b * L + c + ((c >= L) ? (long)7 * L : 0);
    gp[i] = Z + idx * C_DIM + ks * 32 + lg * 8;
  }
  int c0next = cbase;

  // SINGLE staging register set: loaded at iter ct (tile ct+2), ds_written
  // at iter ct+1 — one epoch of vmem-latency cover, 20 regs, short liveness.
  bf16x8 set[5];
  auto ldG = [&]() {
#pragma unroll
    for (int i = 0; i < 5; ++i) set[i] = *(const bf16x8*)gp[i];
    long a = stepEl;
    c0next += 32;
    if (c0next == L) a += extraEl;
#pragma unroll
    for (int i = 0; i < 5; ++i) gp[i] += a;
  };
  auto dsW = [&](int buf) {
#pragma unroll
    for (int i = 0; i < 5; ++i)
      *(bf16x8*)&Bs[buf * 10240 + (w * 5 + i) * 512 + lane * 8] = set[i];
  };

  auto mfmaTile = [&](int buf, f32x4 (&cc)[2][2]) {
#pragma unroll
    for (int rs = 0; rs < 2; ++rs)
#pragma unroll
      for (int cs = 0; cs < 2; ++cs) cc[rs][cs] = (f32x4){0.f, 0.f, 0.f, 0.f};
#pragma unroll
    for (int ks = 0; ks < 10; ++ks) {
      bf16x8 b0 = *(const bf16x8*)&Bs[buf * 10240 + (ks * 2 + 0) * 512 + lane * 8];
      bf16x8 b1 = *(const bf16x8*)&Bs[buf * 10240 + (ks * 2 + 1) * 512 + lane * 8];
#pragma unroll
      for (int rs = 0; rs < 2; ++rs) {
        cc[rs][0] = __builtin_amdgcn_mfma_f32_16x16x32_bf16(afrag[rs][ks], b0, cc[rs][0], 0, 0, 0);
        cc[rs][1] = __builtin_amdgcn_mfma_f32_16x16x32_bf16(afrag[rs][ks], b1, cc[rs][1], 0, 0, 0);
      }
    }
  };

  // wave-uniform slow-tile ranges
  const int rlo = rwave, rhi = rwave + 31;
  int plo = 1, phi = 0;  // empty
  if (d <= 5) {          // L>=64, rwave%32==0 -> rows lie in one half
    plo = (rlo < L) ? rlo + L : rlo - L;
    phi = plo + 31;
  }

  // per-lane per-row state: bias in BASE-2 domain only (m2), sum
  float m2[8], s_[8];
  float pacc = 0.f;
#pragma unroll
  for (int i = 0; i < 8; ++i) { m2[i] = FNEG; s_[i] = 0.f; }

  auto epiSlow = [&](f32x4 (&cp)[2][2], int eclo) {
    const int gc0 = eclo + lr, gc1 = gc0 + 16;
#pragma unroll
    for (int rs = 0; rs < 2; ++rs) {
#pragma unroll
      for (int rg = 0; rg < 4; ++rg) {
        int i = rs * 4 + rg;
        int gr = rwave + rs * 16 + lg * 4 + rg;
        int prt = (gr < L) ? (gr + L) : (gr - L);
        float v0 = cp[rs][0][rg], v1 = cp[rs][1][rg];
        if (gr < M) {
          if (gc0 == prt) pacc += v0;
          if (gc1 == prt) pacc += v1;
        }
        float x0 = (gc0 < M && gc0 != gr) ? v0 * LOG2E : FNEG;
        float x1 = (gc1 < M && gc1 != gr) ? v1 * LOG2E : FNEG;
        float mn = fmaxf(m2[i], fmaxf(x0, x1));
        s_[i] = s_[i] * fast_exp2(m2[i] - mn) +
                fast_exp2(x0 - mn) + fast_exp2(x1 - mn);
        m2[i] = mn;
      }
    }
  };

  auto epiFast = [&](f32x4 (&cp)[2][2]) {
    float flag = FNEG;
#pragma unroll
    for (int rs = 0; rs < 2; ++rs) {
#pragma unroll
      for (int rg = 0; rg < 4; ++rg) {
        int i = rs * 4 + rg;
        float f0 = __builtin_fmaf(cp[rs][0][rg], LOG2E, -m2[i]);
        float f1 = __builtin_fmaf(cp[rs][1][rg], LOG2E, -m2[i]);
        cp[rs][0][rg] = f0;
        cp[rs][1][rg] = f1;
        flag = fmaxf(flag, fmaxf(f0, f1));
      }
    }
    if (__any(flag > 60.f)) {  // rare: raise bias online (f + m2 = v*log2e)
#pragma unroll
      for (int rs = 0; rs < 2; ++rs) {
#pragma unroll
        for (int rg = 0; rg < 4; ++rg) {
          int i = rs * 4 + rg;
          float x0 = cp[rs][0][rg] + m2[i];
          float x1 = cp[rs][1][rg] + m2[i];
          float mn = fmaxf(m2[i], fmaxf(x0, x1));
          s_[i] = s_[i] * fast_exp2(m2[i] - mn) +
                  fast_exp2(x0 - mn) + fast_exp2(x1 - mn);
          m2[i] = mn;
        }
      }
    } else {
#pragma unroll
      for (int rs = 0; rs < 2; ++rs)
#pragma unroll
        for (int rg = 0; rg < 4; ++rg)
          s_[rs * 4 + rg] += fast_exp2(cp[rs][0][rg]) + fast_exp2(cp[rs][1][rg]);
    }
  };

  auto epi = [&](f32x4 (&cp)[2][2], int et) {
    const int eclo = cbase + et * 32, echi = eclo + 31;
    bool slowT = (et == 0) || (d >= 6) ||
                 (echi >= rlo && eclo <= rhi) ||   // diagonal in tile
                 (echi >= plo && eclo <= phi);     // partner col in tile
    if (slowT) epiSlow(cp, eclo); else epiFast(cp);
  };

  // ---- main loop: raw lgkm-only barriers; vmem prefetch crosses them ----
  f32x4 cA[2][2], cB[2][2];
  ldG();                      // tile 0 -> set
  dsW(0);                     // vmcnt-waits ONLY those 5 loads, writes buf 0
  if (ntiles > 1) ldG();      // tile 1 -> set (in flight across barrier)
  barrier_lgkm();

  int br = 0;
  for (int ct = 0; ct < ntiles; ++ct) {
    int bw = (br == 2) ? 0 : br + 1;
    if (ct + 1 < ntiles) dsW(bw);   // set = tile ct+1 (loaded one epoch ago)
    if (ct + 2 < ntiles) ldG();     // tile ct+2 -> set, stays in flight
    if (ct & 1) {
      mfmaTile(br, cB);
      epi(cA, ct - 1);              // overlaps MFMA (independent regs)
    } else {
      mfmaTile(br, cA);
      if (ct > 0) epi(cB, ct - 1);
    }
    barrier_lgkm();                 // lgkmcnt(0) only; no vmcnt drain
    br = bw;
  }
  if ((ntiles - 1) & 1) epi(cB, ntiles - 1); else epi(cA, ntiles - 1);

  // merge (m2,s) across the 16 lr-lanes per row, write per-row-chunk partial
#pragma unroll
  for (int rs = 0; rs < 2; ++rs) {
#pragma unroll
    for (int rg = 0; rg < 4; ++rg) {
      int i = rs * 4 + rg;
      float m = m2[i], s = s_[i];
      float mt = m;
#pragma unroll
      for (int k = 1; k < 16; k <<= 1) mt = fmaxf(mt, __shfl_xor(mt, k));
      float st = s * fast_exp2(m - mt);  // m2=FNEG lanes -> 0
#pragma unroll
      for (int k = 1; k < 16; k <<= 1) st += __shfl_xor(st, k);
      int gr = rwave + rs * 16 + lg * 4 + rg;
      if (gr < M && lr == 0)
        ent[EBASE[d] + ((size_t)(b * M + gr)) * sp + chunk] = make_float2(mt, st);
    }
  }

  // positives (slow tiles only): one atomic per wave
#pragma unroll
  for (int k = 1; k < 64; k <<= 1) pacc += __shfl_xor(pacc, k);
  if (lane == 0) atomicAdd(acc + 1, -pacc * scale);
}

// ---------------- merge column-chunk partials -> temp loss ----------------
// ent holds (m2 = max in base-2 domain, st): LSE_nat = LN2*(m2 + log2(st)).
__global__ __launch_bounds__(256) void merge_kernel(const float2* __restrict__ ent,
                                                    float* __restrict__ acc) {
  constexpr int Ls[NDEPTH] = {2048, 1024, 512, 256, 128, 64, 32, 16, 8, 4, 2, 1};
  constexpr int SP[NDEPTH] = {4, 2, 1, 1, 1, 1, 1, 1, 1, 1, 1, 1};
  constexpr size_t EBASE[NDEPTH] = {0,      131072, 163840, 172032, 176128, 178176,
                                    179200, 179712, 179968, 180096, 180160, 180192};
  constexpr int RBASE[NDEPTH] = {0,     32768, 49152, 57344, 61440, 63488,
                                 64512, 65024, 65280, 65408, 65472, 65504};
  __shared__ float red[4];
  int i = blockIdx.x * 256 + threadIdx.x;
  float partial = 0.f;
  if (i < 65520) {
    int d = 0;
    while (d < 11 && i >= RBASE[d + 1]) ++d;
    int rem = i - RBASE[d];
    int sp = SP[d];
    const float2* e = ent + EBASE[d] + (size_t)rem * sp;
    float mt = FNEG;
    for (int c = 0; c < sp; ++c) mt = fmaxf(mt, e[c].x);
    float st = 0.f;
    for (int c = 0; c < sp; ++c) st += e[c].y * fast_exp2(e[c].x - mt);
    partial = LN2 * (mt + fast_log2(st)) / (16.f * (float)Ls[d]);
  }
#pragma unroll
  for (int k = 1; k < 64; k <<= 1) partial += __shfl_xor(partial, k);
  if ((threadIdx.x & 63) == 0) red[threadIdx.x >> 6] = partial;
  __syncthreads();
  if (threadIdx.x == 0) atomicAdd(acc + 1, red[0] + red[1] + red[2] + red[3]);
}

// ---------------- launch ----------------
extern "C" void kernel_launch(void* const* d_in, const int* in_sizes, int n_in,
                              void* d_out, int out_size, void* d_ws, size_t ws_size,
                              hipStream_t stream) {
  const float* z1 = (const float*)d_in[0];
  const float* z2 = (const float*)d_in[1];
  float* out = (float*)d_out;
  float* acc = (float*)d_ws;                   // [0]=inst, [1]=temp
  float2* ent = (float2*)((char*)d_ws + 256);  // 180208 used, pad to 180224
  unsigned short* pyr = (unsigned short*)((char*)d_ws + 256 + (size_t)180224 * 8);

  constexpr size_t ZOFF[NDEPTH] = {0,        10485760, 15728640, 18350080,
                                   19660800, 20316160, 20643840, 20807680,
                                   20889600, 20930560, 20951040, 20961280};

  transpose_kernel<<<dim3(T_DIM / 32, C_DIM / 32, 16), dim3(32, 8), 0, stream>>>(
      z1, z2, pyr, acc);

  // pools fused: d0->d1..d4, d4->d5..d8, d8->d9..d11
  {
    int L4 = 128, n8 = 16 * L4 * C_DIM / 8;  // 81920
    pool4_kernel<<<dim3((n8 + 255) / 256), 256, 0, stream>>>(
        pyr + ZOFF[0], pyr + ZOFF[1], pyr + ZOFF[2], pyr + ZOFF[3], pyr + ZOFF[4], L4, n8);
  }
  {
    int L4 = 8, n8 = 16 * L4 * C_DIM / 8;    // 5120
    pool4_kernel<<<dim3((n8 + 255) / 256), 256, 0, stream>>>(
        pyr + ZOFF[4], pyr + ZOFF[5], pyr + ZOFF[6], pyr + ZOFF[7], pyr + ZOFF[8], L4, n8);
  }
  {
    int L3 = 1, n8 = 16 * L3 * C_DIM / 8;    // 640
    pool3_kernel<<<dim3((n8 + 255) / 256), 256, 0, stream>>>(
        pyr + ZOFF[8], pyr + ZOFF[9], pyr + ZOFF[10], pyr + ZOFF[11], L3, n8);
  }

  temp_kernel<<<dim3(NBLK_TEMP + NBLK_INST), 256, 0, stream>>>(pyr, ent, acc);
  merge_kernel<<<dim3(256), 256, 0, stream>>>(ent, acc);

  finalize_kernel<<<1, 64, 0, stream>>>(acc, out);
}